// Round 4
// baseline (431.247 us; speedup 1.0000x reference)
//
#include <hip/hip_runtime.h>

#define B_ 64
#define S_ 1024
#define L_ 16
#define T_ 32
#define CH 32          // steps per chunk
#define NC (S_ / CH)   // 32 chunks

__device__ __forceinline__ float fexp2(float x) { return __builtin_amdgcn_exp2f(x); }
__device__ __forceinline__ float flog2(float x) { return __builtin_amdgcn_logf(x); }

// DPP ctrl: quad_perm imm8; row_shr:N=0x110|N; row_ror:N=0x120|N; row_half_mirror=0x141
template <int CTRL, bool BC>
__device__ __forceinline__ float dpp_mov_f(float x) {
    int xi = __float_as_int(x);
    int r = __builtin_amdgcn_update_dpp(xi, xi, CTRL, 0xF, 0xF, BC);
    return __int_as_float(r);
}
__device__ __forceinline__ float dpp_shr1_fill(float x, float fill) {
    int xi = __float_as_int(x), fi = __float_as_int(fill);
    int r = __builtin_amdgcn_update_dpp(fi, xi, 0x111, 0xF, 0xF, false);
    return __int_as_float(r);
}
// reductions within each aligned 16-lane group (verified absmax 0.0 in R1-R3)
__device__ __forceinline__ float row16_sum(float t) {
    t += dpp_mov_f<0xB1, true>(t);
    t += dpp_mov_f<0x4E, true>(t);
    t += dpp_mov_f<0x124, true>(t);
    t += dpp_mov_f<0x128, true>(t);
    return t;
}
__device__ __forceinline__ float row16_max(float t) {
    t = fmaxf(t, dpp_mov_f<0xB1, true>(t));
    t = fmaxf(t, dpp_mov_f<0x4E, true>(t));
    t = fmaxf(t, dpp_mov_f<0x124, true>(t));
    t = fmaxf(t, dpp_mov_f<0x128, true>(t));
    return t;
}

// ---- P1 (fused): per (batch,chunk) R2 + transfer matrix; last block per
// batch runs the combine epilogue (matvec chain + tail + atomicAdd to out).
__global__ __launch_bounds__(256) void p1_kernel(const float* __restrict__ tr,
                                                 const int* __restrict__ tags,
                                                 const int* __restrict__ lens,
                                                 float* __restrict__ Mg,
                                                 float* __restrict__ R2t,
                                                 float* __restrict__ numc,
                                                 int* __restrict__ cnt,
                                                 float* __restrict__ out) {
    __shared__ float R2s[CH * L_];  // 512 floats: R2[local_s][l] (log2 domain)
    __shared__ float vb[2][16];
    __shared__ float numsh;
    __shared__ int ticket_s;
    const int bc = blockIdx.x;
    const int b = bc >> 5, c = bc & 31;
    const int tid = threadIdx.x;
    const int len = lens[b];
    const float LOG2E = 1.4426950408889634f;

    // --- R2 rows: LSE over T=32 for 512 (s,l) rows; 8 lanes x float4 per row.
    const float4* tr4 = reinterpret_cast<const float4*>(tr);
    const size_t base4 = ((size_t)b * 16384 + (size_t)c * 512) * 8;
#pragma unroll 8
    for (int pass = 0; pass < 16; ++pass) {
        float4 v = tr4[base4 + (size_t)pass * 256 + tid];
        float s = fexp2(v.x * LOG2E) + fexp2(v.y * LOG2E) +
                  fexp2(v.z * LOG2E) + fexp2(v.w * LOG2E);
        s += dpp_mov_f<0xB1, true>(s);   // quad xor1
        s += dpp_mov_f<0x4E, true>(s);   // quad xor2
        s += dpp_mov_f<0x141, true>(s);  // half-row mirror -> 8-lane sum
        if ((tid & 7) == 0) R2s[pass * 32 + (tid >> 3)] = flog2(s);
    }

    // --- numerator partial for this chunk (wave 0); lines are L1/L2-hot ---
    if (tid < 64) {
        float nm = 0.f;
        if (tid < 32) {
            int s = c * 32 + tid;
            if (s < len) {
                int tg = tags[b * S_ + s];
                nm = tr[(((size_t)b * S_ + s) * L_) * T_ + tg];  // l = 0
            }
        }
        for (int off = 32; off > 0; off >>= 1) nm += __shfl_xor(nm, off, 64);
        if (tid == 0) numc[b * NC + c] = nm;
    }
    __syncthreads();

    // --- tail R2 rows (only the chunk containing len; len==S -> no tail) ---
    if (c == (len >> 5)) {
        R2t[b * 512 + tid] = R2s[tid];
        R2t[b * 512 + 256 + tid] = R2s[256 + tid];
    }

    // --- 16 basis runs: group G = basis j; lane-in-group kk = window index.
    const int G = tid >> 4;
    const int kk = tid & 15;
    {
        float a2 = R2s[G];
        float wp = (kk == 0) ? 0.f : ((kk == G + 1) ? -a2 : -1e9f);
#pragma unroll 4
        for (int row = 1; row < CH; ++row) {
            float x = wp + R2s[row * 16 + kk];
            float t = fexp2(x);             // dead taps: 2^(-1e9) == 0
            t = row16_sum(t);
            float d = flog2(t);
            a2 += d;
            wp = dpp_shr1_fill(wp, d) - d;  // slide + renormalize (lane0 -> 0)
        }
        Mg[(size_t)bc * 256 + kk * 16 + G] = a2 + wp;  // M[i=kk][j=G]
    }

    // --- epilogue election: last-arriving block of this batch combines ---
    __threadfence();                 // make Mg/R2t/numc visible device-wide
    __syncthreads();
    if (tid == 0) ticket_s = atomicAdd(&cnt[b], 1);
    __syncthreads();
    if (ticket_s != NC - 1) return;
    __threadfence();                 // acquire: don't read stale lines

    const int q = len >> 5, r = len & 31;
    if (tid < 64) {
        float nm = (tid < 32) ? numc[b * NC + tid] : 0.f;
        for (int off = 32; off > 0; off >>= 1) nm += __shfl_xor(nm, off, 64);
        if (tid == 0) numsh = nm;
    }
    if (tid < 16) vb[0][tid] = (tid == 0) ? 0.f : -1e9f;
    __syncthreads();

    // matvec: v'[i] = v0 + mx_i + log2( sum_j 2^(M[i][j] + v[j] - v0 - mx_i) )
    int p = 0;
    const int i16 = tid >> 4, j = tid & 15;
    const float* Mb = Mg + (size_t)b * NC * 256;
    for (int cc = 0; cc < q; ++cc) {
        float vj = vb[p][j], v0 = vb[p][0];
        float x = Mb[cc * 256 + tid] + vj - v0;
        float mx = row16_max(x);                 // finite: j=0 tap
        float t = row16_sum(fexp2(x - mx));
        float nv = v0 + mx + flog2(t);
        if (j == 0) vb[1 - p][i16] = nv;
        __syncthreads();
        p ^= 1;
    }

    // tail: r serial steps by wave 0 (4 redundant 16-lane groups)
    if (tid < 64) {
        float v0 = vb[p][0];
        float wp = vb[p][kk] - v0;
        float a2 = v0;
        const float* Rl = R2t + b * 512;
        for (int t0 = 0; t0 < r; ++t0) {
            float e = fexp2(wp + Rl[t0 * 16 + kk]);
            e = row16_sum(e);
            float d = flog2(e);
            a2 += d;
            wp = dpp_shr1_fill(wp, d) - d;
        }
        if (tid == 0) atomicAdd(out, a2 * 0.6931471805599453f - numsh);
    }
}

extern "C" void kernel_launch(void* const* d_in, const int* in_sizes, int n_in,
                              void* d_out, int out_size, void* d_ws, size_t ws_size,
                              hipStream_t stream) {
    const float* tr = (const float*)d_in[0];
    const int* tags = (const int*)d_in[1];
    const int* lens = (const int*)d_in[2];
    float* out = (float*)d_out;

    // ws layout (floats): Mg [B*NC*256] | R2t [B*512] | numc [B*NC] | cnt [B]
    float* Mg = (float*)d_ws;
    float* R2t = Mg + (size_t)B_ * NC * 256;
    float* numc = R2t + (size_t)B_ * 512;
    int* cnt = (int*)(numc + (size_t)B_ * NC);

    hipMemsetAsync(cnt, 0, B_ * sizeof(int), stream);
    hipMemsetAsync(out, 0, sizeof(float), stream);
    p1_kernel<<<B_ * NC, 256, 0, stream>>>(tr, tags, lens, Mg, R2t, numc, cnt, out);
}

// Round 5
// 209.773 us; speedup vs baseline: 2.0558x; 2.0558x over previous
//
#include <hip/hip_runtime.h>

#define B_ 64
#define S_ 1024
#define L_ 16
#define T_ 32
#define CH 32          // steps per chunk
#define NC (S_ / CH)   // 32 chunks

__device__ __forceinline__ float fexp2(float x) { return __builtin_amdgcn_exp2f(x); }
__device__ __forceinline__ float flog2(float x) { return __builtin_amdgcn_logf(x); }

// DPP ctrl: quad_perm imm8; row_shr:N=0x110|N; row_ror:N=0x120|N; row_half_mirror=0x141
template <int CTRL, bool BC>
__device__ __forceinline__ float dpp_mov_f(float x) {
    int xi = __float_as_int(x);
    int r = __builtin_amdgcn_update_dpp(xi, xi, CTRL, 0xF, 0xF, BC);
    return __int_as_float(r);
}
__device__ __forceinline__ float dpp_shr1_fill(float x, float fill) {
    int xi = __float_as_int(x), fi = __float_as_int(fill);
    int r = __builtin_amdgcn_update_dpp(fi, xi, 0x111, 0xF, 0xF, false);
    return __int_as_float(r);
}
// reductions within each aligned 16-lane group (verified absmax 0.0 in R1-R3)
__device__ __forceinline__ float row16_sum(float t) {
    t += dpp_mov_f<0xB1, true>(t);
    t += dpp_mov_f<0x4E, true>(t);
    t += dpp_mov_f<0x124, true>(t);
    t += dpp_mov_f<0x128, true>(t);
    return t;
}
__device__ __forceinline__ float row16_max(float t) {
    t = fmaxf(t, dpp_mov_f<0xB1, true>(t));
    t = fmaxf(t, dpp_mov_f<0x4E, true>(t));
    t = fmaxf(t, dpp_mov_f<0x124, true>(t));
    t = fmaxf(t, dpp_mov_f<0x128, true>(t));
    return t;
}

// ---- P1: per (batch, chunk): fused R2 computation + 16-basis transfer matrix
// block = 256 threads = 4 waves = 16 groups of 16 lanes (group = basis j).
// NO cross-block fences (round-4 lesson: agent-scope __threadfence = L2
// writeback storm, 4x regression); p1->p2 ordering comes from the stream.
__global__ __launch_bounds__(256) void p1_kernel(const float* __restrict__ tr,
                                                 const int* __restrict__ tags,
                                                 const int* __restrict__ lens,
                                                 float* __restrict__ Mg,
                                                 float* __restrict__ R2t,
                                                 float* __restrict__ numc,
                                                 float* __restrict__ out) {
    __shared__ float R2s[CH * L_];  // 512 floats: R2[local_s][l] (log2 domain)
    const int bc = blockIdx.x;
    const int b = bc >> 5, c = bc & 31;
    const int tid = threadIdx.x;
    if (bc == 0 && tid == 0) out[0] = 0.f;  // P2 runs after P1 (stream order)

    const int len = lens[b];
    const float LOG2E = 1.4426950408889634f;

    // --- R2 rows: LSE over T=32 for 512 (s,l) rows; 8 lanes x float4 per row.
    const float4* tr4 = reinterpret_cast<const float4*>(tr);
    const size_t base4 = ((size_t)b * 16384 + (size_t)c * 512) * 8;
#pragma unroll 8
    for (int pass = 0; pass < 16; ++pass) {
        float4 v = tr4[base4 + (size_t)pass * 256 + tid];
        float s = fexp2(v.x * LOG2E) + fexp2(v.y * LOG2E) +
                  fexp2(v.z * LOG2E) + fexp2(v.w * LOG2E);
        s += dpp_mov_f<0xB1, true>(s);   // quad xor1
        s += dpp_mov_f<0x4E, true>(s);   // quad xor2
        s += dpp_mov_f<0x141, true>(s);  // half-row mirror -> 8-lane sum
        if ((tid & 7) == 0) R2s[pass * 32 + (tid >> 3)] = flog2(s);
    }

    // --- numerator partial for this chunk (wave 0) ---
    if (tid < 64) {
        float nm = 0.f;
        if (tid < 32) {
            int s = c * 32 + tid;
            if (s < len) {
                int tg = tags[b * S_ + s];
                nm = tr[(((size_t)b * S_ + s) * L_) * T_ + tg];  // l = 0
            }
        }
        for (int off = 32; off > 0; off >>= 1) nm += __shfl_xor(nm, off, 64);
        if (tid == 0) numc[b * NC + c] = nm;
    }
    __syncthreads();

    // --- tail R2 rows for this batch (only the chunk containing len) ---
    if (c == (len >> 5)) {  // len>>5 in [0,32]; c in [0,31]
        R2t[b * 512 + tid] = R2s[tid];
        R2t[b * 512 + 256 + tid] = R2s[256 + tid];
    }

    // --- 16 basis runs: group G = basis j; lane-in-group kk = window index.
    // First step done analytically: alpha[cS+1] = R2[row0][j].
    const int G = tid >> 4;
    const int kk = tid & 15;
    float a2 = R2s[G];
    float wp = (kk == 0) ? 0.f : ((kk == G + 1) ? -a2 : -1e9f);
#pragma unroll 4
    for (int row = 1; row < CH; ++row) {
        float x = wp + R2s[row * 16 + kk];
        float t = fexp2(x);             // dead taps: 2^(-1e9) == 0
        t = row16_sum(t);
        float d = flog2(t);
        a2 += d;
        wp = dpp_shr1_fill(wp, d) - d;  // slide + renormalize (lane0 -> 0)
    }
    // M[i][j] = a2 + wp[i]; this lane holds i=kk, j=G
    Mg[(size_t)bc * 256 + kk * 16 + G] = a2 + wp;
}

// ---- P2: per batch: q = len/32 LSE-matvecs then <=31 tail steps ------------
// No LDS staging of M: register-prefetch the next chunk matrix (L2/L3-hot,
// 1 KB coalesced) while the current matvec chain runs; reads only q matrices.
__global__ __launch_bounds__(256) void p2_kernel(const float* __restrict__ Mg,
                                                 const float* __restrict__ R2t,
                                                 const float* __restrict__ numc,
                                                 const int* __restrict__ lens,
                                                 float* __restrict__ out) {
    __shared__ float R2l[CH * L_];  // tail rows
    __shared__ float vb[2][16];
    __shared__ float numsh;
    const int b = blockIdx.x, tid = threadIdx.x;
    const int len = lens[b];
    const int q = len >> 5, r = len & 31;

    R2l[tid] = R2t[b * 512 + tid];
    if (tid < 64) {
        float nm = (tid < 32) ? numc[b * NC + tid] : 0.f;
        for (int off = 32; off > 0; off >>= 1) nm += __shfl_xor(nm, off, 64);
        if (tid == 0) numsh = nm;
    }
    if (tid < 16) vb[0][tid] = (tid == 0) ? 0.f : -1e9f;
    const float* Mb = Mg + (size_t)b * NC * 256;
    float mcur = (q > 0) ? Mb[tid] : 0.f;
    R2l[256 + tid] = R2t[b * 512 + 256 + tid];
    __syncthreads();

    // matvec: v'[i] = v0 + mx_i + log2( sum_j 2^(M[i][j] + v[j] - v0 - mx_i) )
    int p = 0;
    const int i16 = tid >> 4, j = tid & 15;
    for (int cc = 0; cc < q; ++cc) {
        float mnext = (cc + 1 < q) ? Mb[(cc + 1) * 256 + tid] : 0.f;  // prefetch
        float vj = vb[p][j], v0 = vb[p][0];
        float x = mcur + vj - v0;
        float mx = row16_max(x);                 // per-group max (finite: j=0 tap)
        float t = row16_sum(fexp2(x - mx));
        float nv = v0 + mx + flog2(t);
        if (j == 0) vb[1 - p][i16] = nv;
        __syncthreads();
        p ^= 1;
        mcur = mnext;
    }

    // tail: r serial steps by wave 0 (4 redundant 16-lane groups)
    if (tid < 64) {
        const int kk = tid & 15;
        float v0 = vb[p][0];
        float wp = vb[p][kk] - v0;
        float a2 = v0;
        for (int t0 = 0; t0 < r; ++t0) {
            float x = wp + R2l[t0 * 16 + kk];
            float e = fexp2(x);
            e = row16_sum(e);
            float d = flog2(e);
            a2 += d;
            wp = dpp_shr1_fill(wp, d) - d;
        }
        if (tid == 0) atomicAdd(out, a2 * 0.6931471805599453f - numsh);
    }
}

extern "C" void kernel_launch(void* const* d_in, const int* in_sizes, int n_in,
                              void* d_out, int out_size, void* d_ws, size_t ws_size,
                              hipStream_t stream) {
    const float* tr = (const float*)d_in[0];
    const int* tags = (const int*)d_in[1];
    const int* lens = (const int*)d_in[2];
    float* out = (float*)d_out;

    // ws layout (floats): Mg [B*NC*256] | R2t [B*512] | numc [B*NC]  (~2.25 MB)
    float* Mg = (float*)d_ws;
    float* R2t = Mg + (size_t)B_ * NC * 256;
    float* numc = R2t + (size_t)B_ * 512;

    p1_kernel<<<B_ * NC, 256, 0, stream>>>(tr, tags, lens, Mg, R2t, numc, out);
    p2_kernel<<<B_, 256, 0, stream>>>(Mg, R2t, numc, lens, out);
}